// Round 10
// baseline (184.275 us; speedup 1.0000x reference)
//
#include <hip/hip_runtime.h>
#include <hip/hip_cooperative_groups.h>

namespace cg = cooperative_groups;

#define MB   2048   // model batches
#define NP   8192   // num points (scan length)
#define NF   8      // number of functions
#define RM   51     // removed leading iterations
#define NCH  64     // chunks per batch
#define CH   128    // NP / NCH, steps per chunk
#define COLS 33     // u16 words per tile row (32 used + pad)

typedef unsigned int   u32;
typedef unsigned short u16;

// group g (steps 4g..4g+3) lives at column 4*(g&7)+(g>>3); staging thread
// (x8,yy) at seg writes word w=seg*8+x8 -> col 4*x8+seg. 4*(8*(g>>3))+4*(g&7)=4g.
#define CMAP(g) ((((g) & 7) << 2) | ((g) >> 3))

// ws: mapsA float4[NCH*MB] @0 (2MB) | mapsC float2[NCH*MB] @2MB (1MB) | pe float2 @3MB (1MB)

__device__ __forceinline__ void build_tbl(float4* tA, float4* tB, const float* W,
                                          const float* B, const float* OPS, int tid)
{
    if (tid < NF) {
        tA[tid] = make_float4(W[tid*4+0], W[tid*4+1], W[tid*4+2], W[tid*4+3]);
        tB[tid] = make_float4(B[tid*2+0], B[tid*2+1], OPS ? OPS[tid] : 0.f, 0.f);
    }
}

// stage one 32-step segment as nibble codes (3-bit f x4 per u16)
__device__ __forceinline__ void stage_u16(
    const int* __restrict__ idxg, u16 (*tile)[COLS],
    int c, int b0, int x8, int yy, int seg)
{
    #pragma unroll
    for (int p = 0; p < 8; ++p) {
        const int row = yy + p * 32;       // 8 lanes x int4 = 128B/row: coalesced
        const int4 v = *(const int4*)(idxg + (size_t)(b0 + row) * NP
                                      + c * CH + seg * 32 + x8 * 4);
        tile[row][4 * x8 + seg] = (u16)(v.x | (v.y << 4) | (v.z << 8) | (v.w << 12));
    }
}

// compose 128 steps from the nibble tile (overlapping the staging of later segs)
__device__ __forceinline__ void compose_chunk(
    const int* __restrict__ idxg, u16 (*tile)[COLS],
    const float4* tA, const float4* tB,
    int c, int b0, int tid, int x8, int yy,
    float4& Aout, float2& Cout)
{
    float a00 = 1.f, a01 = 0.f, a10 = 0.f, a11 = 1.f, c0 = 0.f, c1 = 0.f;
    for (int seg = 0; seg < 4; ++seg) {
        if (seg < 3) stage_u16(idxg, tile, c, b0, x8, yy, seg + 1);
        #pragma unroll
        for (int j = 0; j < 8; ++j) {
            const u32 pc = tile[tid][CMAP(seg * 8 + j)];
            #pragma unroll
            for (int e = 0; e < 4; ++e) {
                const int f = (pc >> (4 * e)) & 7;
                const float4 w  = tA[f];     // 8x16B table: conflict-free b128
                const float4 bb = tB[f];
                const float na00 = w.x*a00 + w.y*a10;
                const float na01 = w.x*a01 + w.y*a11;
                const float na10 = w.z*a00 + w.w*a10;
                const float na11 = w.z*a01 + w.w*a11;
                const float nc0  = w.x*c0  + w.y*c1 + bb.x;
                const float nc1  = w.z*c0  + w.w*c1 + bb.y;
                a00 = na00; a01 = na01; a10 = na10; a11 = na11; c0 = nc0; c1 = nc1;
            }
        }
        __syncthreads();                    // publish next seg's staging
    }
    Aout = make_float4(a00, a01, a10, a11);
    Cout = make_float2(c0, c1);
}

// replay 128 steps from the nibble tile, direct strided stores
__device__ __forceinline__ void replay_chunk(
    const u16 (*tile)[COLS], const float4* tA, const float4* tB,
    float2 p, float* __restrict__ out, int c, int b, int tid)
{
    float* o = out + ((long long)c * CH - RM) * (MB * 3) + (long long)b * 3;
    const bool chk = (c == 0);
    for (int g = 0; g < 32; ++g) {
        const u32 pc = tile[tid][CMAP(g)];
        #pragma unroll
        for (int s = 0; s < 4; ++s) {
            const int f = (pc >> (4 * s)) & 7;
            const float4 w  = tA[f];
            const float4 bb = tB[f];
            const float nx = w.x * p.x + w.y * p.y + bb.x;
            const float ny = w.z * p.x + w.w * p.y + bb.y;
            p.x = nx; p.y = ny;
            if (!chk || (g * 4 + s) >= RM) {
                o[0] = nx; o[1] = ny; o[2] = bb.z;
            }
            o += MB * 3;
        }
    }
}

// ---------------- fused cooperative kernel (17.2 KB LDS) ----------------
__global__ __launch_bounds__(256, 2) void ifs_coop(
    const float2* __restrict__ point, const float* __restrict__ W,
    const float* __restrict__ B, const float* __restrict__ OPS,
    const int* __restrict__ idxg,
    float4* __restrict__ mapsA, float2* __restrict__ mapsC,
    float2* __restrict__ pe, float* __restrict__ out)
{
    __shared__ u16 tile[256][COLS];                 // 16.9 KB, persists A -> C
    __shared__ __align__(16) float4 tA[NF], tB[NF];

    const int tid = threadIdx.x;
    const int c   = blockIdx.x >> 3;
    const int b0  = (blockIdx.x & 7) << 8;
    const int b   = b0 + tid;
    const int x8  = tid & 7, yy = tid >> 3;

    build_tbl(tA, tB, W, B, OPS, tid);
    stage_u16(idxg, tile, c, b0, x8, yy, 0);
    __syncthreads();

    float4 A; float2 C;
    compose_chunk(idxg, tile, tA, tB, c, b0, tid, x8, yy, A, C);
    mapsA[(size_t)c * MB + b] = A;
    mapsC[(size_t)c * MB + b] = C;

    cg::grid_group grid = cg::this_grid();
    grid.sync();                                    // all chunk maps visible

    if (c == 0) {                                   // blocks 0..7 cover all batches
        float2 p = point[b];
        float4 A0[8], A1[8]; float2 C0[8], C1[8];
        #pragma unroll
        for (int k = 0; k < 8; ++k) {
            A0[k] = mapsA[(size_t)k * MB + b];
            C0[k] = mapsC[(size_t)k * MB + b];
        }
        for (int g = 0; g < 8; ++g) {
            if (g < 7) {
                #pragma unroll
                for (int k = 0; k < 8; ++k) {
                    A1[k] = mapsA[(size_t)((g + 1) * 8 + k) * MB + b];
                    C1[k] = mapsC[(size_t)((g + 1) * 8 + k) * MB + b];
                }
            }
            #pragma unroll
            for (int k = 0; k < 8; ++k) {
                pe[(size_t)(g * 8 + k) * MB + b] = p;
                const float nx = A0[k].x * p.x + A0[k].y * p.y + C0[k].x;
                const float ny = A0[k].z * p.x + A0[k].w * p.y + C0[k].y;
                p.x = nx; p.y = ny;
            }
            #pragma unroll
            for (int k = 0; k < 8; ++k) { A0[k] = A1[k]; C0[k] = C1[k]; }
        }
    }
    grid.sync();                                    // pe visible

    const float2 p = pe[(size_t)c * MB + b];
    replay_chunk(tile, tA, tB, p, out, c, b, tid);
}

// ---------------- fallback 3-kernel pipeline (proven structure) ----------------
__global__ __launch_bounds__(256) void fb_p1(
    const int* __restrict__ idxg, const float* __restrict__ W,
    const float* __restrict__ B,
    float4* __restrict__ mapsA, float2* __restrict__ mapsC)
{
    __shared__ u16 tile[256][COLS];
    __shared__ __align__(16) float4 tA[NF], tB[NF];
    const int tid = threadIdx.x;
    const int c   = blockIdx.x >> 3;
    const int b0  = (blockIdx.x & 7) << 8;
    const int x8  = tid & 7, yy = tid >> 3;
    build_tbl(tA, tB, W, B, nullptr, tid);
    stage_u16(idxg, tile, c, b0, x8, yy, 0);
    __syncthreads();
    float4 A; float2 C;
    compose_chunk(idxg, tile, tA, tB, c, b0, tid, x8, yy, A, C);
    mapsA[(size_t)c * MB + b0 + tid] = A;
    mapsC[(size_t)c * MB + b0 + tid] = C;
}

__global__ __launch_bounds__(64) void fb_p2(
    const float2* __restrict__ point, const float4* __restrict__ mapsA,
    const float2* __restrict__ mapsC, float2* __restrict__ pe)
{
    const int b = blockIdx.x * 64 + threadIdx.x;
    float2 p = point[b];
    float4 A0[8], A1[8]; float2 C0[8], C1[8];
    #pragma unroll
    for (int k = 0; k < 8; ++k) {
        A0[k] = mapsA[(size_t)k * MB + b];
        C0[k] = mapsC[(size_t)k * MB + b];
    }
    for (int g = 0; g < 8; ++g) {
        if (g < 7) {
            #pragma unroll
            for (int k = 0; k < 8; ++k) {
                A1[k] = mapsA[(size_t)((g + 1) * 8 + k) * MB + b];
                C1[k] = mapsC[(size_t)((g + 1) * 8 + k) * MB + b];
            }
        }
        #pragma unroll
        for (int k = 0; k < 8; ++k) {
            pe[(size_t)(g * 8 + k) * MB + b] = p;
            const float nx = A0[k].x * p.x + A0[k].y * p.y + C0[k].x;
            const float ny = A0[k].z * p.x + A0[k].w * p.y + C0[k].y;
            p.x = nx; p.y = ny;
        }
        #pragma unroll
        for (int k = 0; k < 8; ++k) { A0[k] = A1[k]; C0[k] = C1[k]; }
    }
}

__global__ __launch_bounds__(256) void fb_p3(
    const int* __restrict__ idxg, const float* __restrict__ W,
    const float* __restrict__ B, const float* __restrict__ OPS,
    const float2* __restrict__ pe, float* __restrict__ out)
{
    __shared__ u16 tile[256][COLS];
    __shared__ __align__(16) float4 tA[NF], tB[NF];
    const int tid = threadIdx.x;
    const int c   = blockIdx.x >> 3;
    const int b0  = (blockIdx.x & 7) << 8;
    const int x8  = tid & 7, yy = tid >> 3;
    build_tbl(tA, tB, W, B, OPS, tid);
    #pragma unroll
    for (int seg = 0; seg < 4; ++seg) stage_u16(idxg, tile, c, b0, x8, yy, seg);
    __syncthreads();
    const float2 p = pe[(size_t)c * MB + b0 + tid];
    replay_chunk(tile, tA, tB, p, out, c, b0 + tid, tid);
}

extern "C" void kernel_launch(void* const* d_in, const int* in_sizes, int n_in,
                              void* d_out, int out_size, void* d_ws, size_t ws_size,
                              hipStream_t stream) {
    const float2* point = (const float2*)d_in[0];  // [2048,2,1]
    const float*  W     = (const float*)d_in[1];   // [8,2,2]
    const float*  B     = (const float*)d_in[2];   // [8,2,1]
    const float*  OPS   = (const float*)d_in[3];   // [8]
    const int*    idx   = (const int*)  d_in[4];   // [2048,8192]
    float*        out   = (float*)d_out;           // [(8192-51)*2048, 3]

    char* ws = (char*)d_ws;
    float4* mapsA = (float4*)(ws);                                 // 2 MB
    float2* mapsC = (float2*)(ws + (size_t)NCH * MB * 16);         // 1 MB
    float2* pe    = (float2*)(ws + (size_t)NCH * MB * 24);         // 1 MB

    void* args[] = { (void*)&point, (void*)&W, (void*)&B, (void*)&OPS, (void*)&idx,
                     (void*)&mapsA, (void*)&mapsC, (void*)&pe, (void*)&out };
    const hipError_t e = hipLaunchCooperativeKernel(
        (const void*)ifs_coop, dim3(NCH * (MB / 256)), dim3(256), args, 0, stream);
    if (e != hipSuccess) {
        (void)hipGetLastError();   // clear sticky error; run proven pipeline
        fb_p1<<<NCH * (MB / 256), 256, 0, stream>>>(idx, W, B, mapsA, mapsC);
        fb_p2<<<MB / 64, 64, 0, stream>>>(point, mapsA, mapsC, pe);
        fb_p3<<<NCH * (MB / 256), 256, 0, stream>>>(idx, W, B, OPS, pe, out);
    }
}

// Round 11
// 86.047 us; speedup vs baseline: 2.1416x; 2.1416x over previous
//
#include <hip/hip_runtime.h>

#define MB   2048   // model batches
#define NP   8192   // num points (scan length)
#define NF   8      // number of functions
#define RM   51     // removed leading iterations
#define NCH  128    // chunks per batch
#define CH   64     // NP / NCH, steps per chunk
#define COLS 17     // u16 words per tile row (16 used + pad)

typedef float          f32x4 __attribute__((ext_vector_type(4)));
typedef unsigned int   u32;
typedef unsigned short u16;

// word w = seg*8 + x8 (seg in {0,1}) holds steps 4w..4w+3; stored at column
// 2*(w&7) + (w>>3). Staging banks ~2-way; replay reads (34*tid+2g)/4 %32:
// 34t mod 128 takes 64 distinct even values over t=0..63 -> exactly 2-way = free.
#define CMAP(g) ((((g) & 7) << 1) | ((g) >> 3))

// ws: mapsA float4[NCH*MB] @0 (4MB) | mapsC float2[NCH*MB] @4MB (2MB)
//     pe float2[NCH*MB] @6MB (2MB)

__device__ __forceinline__ void build_tbl(float4* tA, float4* tB, const float* W,
                                          const float* B, const float* OPS, int tid)
{
    if (tid < NF) {
        tA[tid] = make_float4(W[tid*4+0], W[tid*4+1], W[tid*4+2], W[tid*4+3]);
        tB[tid] = make_float4(B[tid*2+0], B[tid*2+1], OPS ? OPS[tid] : 0.f, 0.f);
    }
}

// stage one 32-step segment as nibble codes (4-bit f x4 per u16), coalesced int4
__device__ __forceinline__ void stage_u16(
    const int* __restrict__ idxg, u16 (*tile)[COLS],
    int c, int b0, int x8, int yy, int seg)
{
    #pragma unroll
    for (int p = 0; p < 8; ++p) {
        const int row = yy + p * 32;       // 8 lanes x int4 = 128B/row: coalesced
        const int4 v = *(const int4*)(idxg + (size_t)(b0 + row) * NP
                                      + c * CH + seg * 32 + x8 * 4);
        tile[row][2 * x8 + seg] = (u16)(v.x | (v.y << 4) | (v.z << 8) | (v.w << 12));
    }
}

// ---------------- Phase 1: compose 64-step chunk maps ----------------
__global__ __launch_bounds__(256, 4) void ifs_phase1(
    const int* __restrict__ idxg, const float* __restrict__ W,
    const float* __restrict__ B,
    float4* __restrict__ mapsA, float2* __restrict__ mapsC)
{
    __shared__ u16 tile[256][COLS];                 // 8.7 KB
    __shared__ __align__(16) float4 tA[NF], tB[NF]; // conflict-free b128 broadcast
    const int tid = threadIdx.x;
    const int c   = blockIdx.x >> 3;
    const int b0  = (blockIdx.x & 7) << 8;
    const int x8  = tid & 7, yy = tid >> 3;

    build_tbl(tA, tB, W, B, nullptr, tid);
    stage_u16(idxg, tile, c, b0, x8, yy, 0);
    __syncthreads();                                // stage(0) + tables visible

    float a00 = 1.f, a01 = 0.f, a10 = 0.f, a11 = 1.f, c0 = 0.f, c1 = 0.f;
    for (int seg = 0; seg < 2; ++seg) {
        if (seg == 0) stage_u16(idxg, tile, c, b0, x8, yy, 1);  // overlap fetch
        #pragma unroll
        for (int j = 0; j < 8; ++j) {
            const u32 pc = tile[tid][CMAP(seg * 8 + j)];
            #pragma unroll
            for (int e = 0; e < 4; ++e) {
                const int f = (pc >> (4 * e)) & 7;
                const float4 w  = tA[f];
                const float4 bb = tB[f];
                const float na00 = w.x*a00 + w.y*a10;
                const float na01 = w.x*a01 + w.y*a11;
                const float na10 = w.z*a00 + w.w*a10;
                const float na11 = w.z*a01 + w.w*a11;
                const float nc0  = w.x*c0  + w.y*c1 + bb.x;
                const float nc1  = w.z*c0  + w.w*c1 + bb.y;
                a00 = na00; a01 = na01; a10 = na10; a11 = na11; c0 = nc0; c1 = nc1;
            }
        }
        __syncthreads();                            // publish staged seg
    }
    mapsA[(size_t)c * MB + b0 + tid] = make_float4(a00, a01, a10, a11);
    mapsC[(size_t)c * MB + b0 + tid] = make_float2(c0, c1);
}

// ---------------- Phase 2: sequential scan over 128 chunk maps ----------------
__global__ __launch_bounds__(64) void ifs_phase2(
    const float2* __restrict__ point, const float4* __restrict__ mapsA,
    const float2* __restrict__ mapsC, float2* __restrict__ pe)
{
    const int b = blockIdx.x * 64 + threadIdx.x;    // 32 blocks -> 32 CUs
    float2 p = point[b];
    float4 A0[8], A1[8]; float2 C0[8], C1[8];
    #pragma unroll
    for (int k = 0; k < 8; ++k) {
        A0[k] = mapsA[(size_t)k * MB + b];
        C0[k] = mapsC[(size_t)k * MB + b];
    }
    for (int g = 0; g < 16; ++g) {                  // 16 x 8-deep prefetch groups
        if (g < 15) {
            #pragma unroll
            for (int k = 0; k < 8; ++k) {
                A1[k] = mapsA[(size_t)((g + 1) * 8 + k) * MB + b];
                C1[k] = mapsC[(size_t)((g + 1) * 8 + k) * MB + b];
            }
        }
        #pragma unroll
        for (int k = 0; k < 8; ++k) {
            pe[(size_t)(g * 8 + k) * MB + b] = p;
            const float nx = A0[k].x * p.x + A0[k].y * p.y + C0[k].x;
            const float ny = A0[k].z * p.x + A0[k].w * p.y + C0[k].y;
            p.x = nx; p.y = ny;
        }
        #pragma unroll
        for (int k = 0; k < 8; ++k) { A0[k] = A1[k]; C0[k] = C1[k]; }
    }
}

// ---------------- Phase 3: replay, transpose-coalesced nt output ----------------
__global__ __launch_bounds__(256, 4) void ifs_phase3(
    const int* __restrict__ idxg, const float* __restrict__ W,
    const float* __restrict__ B, const float* __restrict__ OPS,
    const float2* __restrict__ pe, float* __restrict__ out)
{
    __shared__ u16 tile[256][COLS];                      // 8.7 KB
    __shared__ __align__(16) float sbuf[2][4][256][3];   // ping-pong transpose 24 KB
    __shared__ __align__(16) float4 tA[NF], tB[NF];
    const int tid = threadIdx.x;
    const int c   = blockIdx.x >> 3;
    const int b0  = (blockIdx.x & 7) << 8;
    const int x8  = tid & 7, yy = tid >> 3;

    build_tbl(tA, tB, W, B, OPS, tid);
    stage_u16(idxg, tile, c, b0, x8, yy, 0);             // idx re-read: L3-resident
    stage_u16(idxg, tile, c, b0, x8, yy, 1);

    float2 p = pe[(size_t)c * MB + b0 + tid];

    // store-side decomposition: f32x4 k covers flat words w=4*(tid+256k) of the
    // 4x256x3-word group tile; step s=w/768, col r=w%768
    int s_[3];
    long long off[3];
    #pragma unroll
    for (int k = 0; k < 3; ++k) {
        const int w = 4 * (tid + 256 * k);
        s_[k] = w / 768;
        const int r = w - s_[k] * 768;
        off[k] = (long long)(c * CH + s_[k] - RM) * (MB * 3) + b0 * 3 + r;
    }
    const bool chk = (c == 0);
    __syncthreads();                                     // tile + tables visible

    for (int g = 0; g < 16; ++g) {                       // 16 groups x 4 steps
        const int buf = g & 1;
        const u32 pc = tile[tid][CMAP(g)];
        #pragma unroll
        for (int s = 0; s < 4; ++s) {
            const int f = (pc >> (4 * s)) & 7;
            const float4 w  = tA[f];
            const float4 bb = tB[f];
            const float nx = w.x * p.x + w.y * p.y + bb.x;
            const float ny = w.z * p.x + w.w * p.y + bb.y;
            p.x = nx; p.y = ny;
            sbuf[buf][s][tid][0] = nx;                   // stride-3 b32: 2-way = free
            sbuf[buf][s][tid][1] = ny;
            sbuf[buf][s][tid][2] = bb.z;
        }
        __syncthreads();                                 // one barrier per group
        const float* flat = &sbuf[buf][0][0][0];
        #pragma unroll
        for (int k = 0; k < 3; ++k) {
            if (!chk || (g * 4 + s_[k]) >= RM) {
                const f32x4 v = *(const f32x4*)(flat + 4 * (tid + 256 * k));
                __builtin_nontemporal_store(v, (f32x4*)(out + off[k]));
            }
            off[k] += 4LL * (MB * 3);
        }
    }
}

extern "C" void kernel_launch(void* const* d_in, const int* in_sizes, int n_in,
                              void* d_out, int out_size, void* d_ws, size_t ws_size,
                              hipStream_t stream) {
    const float2* point = (const float2*)d_in[0];  // [2048,2,1]
    const float*  W     = (const float*)d_in[1];   // [8,2,2]
    const float*  B     = (const float*)d_in[2];   // [8,2,1]
    const float*  OPS   = (const float*)d_in[3];   // [8]
    const int*    idx   = (const int*)  d_in[4];   // [2048,8192]
    float*        out   = (float*)d_out;           // [(8192-51)*2048, 3]

    char* ws = (char*)d_ws;
    float4* mapsA = (float4*)(ws);                                 // 4 MB
    float2* mapsC = (float2*)(ws + (size_t)NCH * MB * 16);         // 2 MB
    float2* pe    = (float2*)(ws + (size_t)NCH * MB * 24);         // 2 MB

    ifs_phase1<<<NCH * (MB / 256), 256, 0, stream>>>(idx, W, B, mapsA, mapsC);
    ifs_phase2<<<MB / 64, 64, 0, stream>>>(point, mapsA, mapsC, pe);
    ifs_phase3<<<NCH * (MB / 256), 256, 0, stream>>>(idx, W, B, OPS, pe, out);
}

// Round 12
// 75.528 us; speedup vs baseline: 2.4398x; 1.1393x over previous
//
#include <hip/hip_runtime.h>

#define MB   2048   // model batches
#define NP   8192   // num points (scan length)
#define NF   8      // number of functions
#define RM   51     // removed leading iterations
#define NCH  64     // chunks per batch
#define CH   128    // NP / NCH, steps per chunk
#define COLS 33     // u16 words per tile row (32 used + pad)

typedef float          f32x4 __attribute__((ext_vector_type(4)));
typedef unsigned int   u32;
typedef unsigned short u16;

// word w = seg*8 + x8 (seg 0..3) holds steps 4w..4w+3, stored at col 4*x8+seg.
// Replay read tile[tid][CMAP(g)]: dword (33*tid+col)/2 -> exactly 2-way = free.
#define CMAP(g) ((((g) & 7) << 2) | ((g) >> 3))

// ws: mapsA float4[NCH*MB] @0 (2MB) | mapsC float2[NCH*MB] @2MB (1MB) | pe @3MB (1MB)

__device__ __forceinline__ void build_tbl(float4* tA, float4* tB, const float* W,
                                          const float* B, const float* OPS, int tid)
{
    if (tid < NF) {
        tA[tid] = make_float4(W[tid*4+0], W[tid*4+1], W[tid*4+2], W[tid*4+3]);
        tB[tid] = make_float4(B[tid*2+0], B[tid*2+1], OPS ? OPS[tid] : 0.f, 0.f);
    }
}

// stage one 32-step segment as nibble codes (4-bit f x4 per u16), coalesced int4
__device__ __forceinline__ void stage_u16(
    const int* __restrict__ idxg, u16 (*tile)[COLS],
    int c, int b0, int x8, int yy, int seg)
{
    #pragma unroll
    for (int p = 0; p < 8; ++p) {
        const int row = yy + p * 32;       // 8 lanes x int4 = 128B/row: coalesced
        const int4 v = *(const int4*)(idxg + (size_t)(b0 + row) * NP
                                      + c * CH + seg * 32 + x8 * 4);
        tile[row][4 * x8 + seg] = (u16)(v.x | (v.y << 4) | (v.z << 8) | (v.w << 12));
    }
}

// ---------------- Phase 1: compose 128-step chunk maps ----------------
__global__ __launch_bounds__(256, 4) void ifs_phase1(
    const int* __restrict__ idxg, const float* __restrict__ W,
    const float* __restrict__ B,
    float4* __restrict__ mapsA, float2* __restrict__ mapsC)
{
    __shared__ u16 tile[256][COLS];                 // 16.9 KB
    __shared__ __align__(16) float4 tA[NF], tB[NF]; // conflict-free b128 broadcast
    const int tid = threadIdx.x;
    const int c   = blockIdx.x >> 3;
    const int b0  = (blockIdx.x & 7) << 8;
    const int x8  = tid & 7, yy = tid >> 3;

    build_tbl(tA, tB, W, B, nullptr, tid);
    stage_u16(idxg, tile, c, b0, x8, yy, 0);
    __syncthreads();                                // stage(0) + tables visible

    float a00 = 1.f, a01 = 0.f, a10 = 0.f, a11 = 1.f, c0 = 0.f, c1 = 0.f;
    for (int seg = 0; seg < 4; ++seg) {
        if (seg < 3) stage_u16(idxg, tile, c, b0, x8, yy, seg + 1);  // overlap
        #pragma unroll
        for (int j = 0; j < 8; ++j) {
            const u32 pc = tile[tid][CMAP(seg * 8 + j)];
            #pragma unroll
            for (int e = 0; e < 4; ++e) {
                const int f = (pc >> (4 * e)) & 7;
                const float4 w  = tA[f];
                const float4 bb = tB[f];
                const float na00 = w.x*a00 + w.y*a10;
                const float na01 = w.x*a01 + w.y*a11;
                const float na10 = w.z*a00 + w.w*a10;
                const float na11 = w.z*a01 + w.w*a11;
                const float nc0  = w.x*c0  + w.y*c1 + bb.x;
                const float nc1  = w.z*c0  + w.w*c1 + bb.y;
                a00 = na00; a01 = na01; a10 = na10; a11 = na11; c0 = nc0; c1 = nc1;
            }
        }
        __syncthreads();                            // publish staged seg
    }
    mapsA[(size_t)c * MB + b0 + tid] = make_float4(a00, a01, a10, a11);
    mapsC[(size_t)c * MB + b0 + tid] = make_float2(c0, c1);
}

// ---------------- Phase 2: sequential scan over 64 chunk maps ----------------
__global__ __launch_bounds__(64) void ifs_phase2(
    const float2* __restrict__ point, const float4* __restrict__ mapsA,
    const float2* __restrict__ mapsC, float2* __restrict__ pe)
{
    const int b = blockIdx.x * 64 + threadIdx.x;    // 32 blocks -> 32 CUs
    float2 p = point[b];
    float4 A0[8], A1[8]; float2 C0[8], C1[8];
    #pragma unroll
    for (int k = 0; k < 8; ++k) {
        A0[k] = mapsA[(size_t)k * MB + b];
        C0[k] = mapsC[(size_t)k * MB + b];
    }
    for (int g = 0; g < 8; ++g) {                   // 8 x 8-deep prefetch groups
        if (g < 7) {
            #pragma unroll
            for (int k = 0; k < 8; ++k) {
                A1[k] = mapsA[(size_t)((g + 1) * 8 + k) * MB + b];
                C1[k] = mapsC[(size_t)((g + 1) * 8 + k) * MB + b];
            }
        }
        #pragma unroll
        for (int k = 0; k < 8; ++k) {
            pe[(size_t)(g * 8 + k) * MB + b] = p;
            const float nx = A0[k].x * p.x + A0[k].y * p.y + C0[k].x;
            const float ny = A0[k].z * p.x + A0[k].w * p.y + C0[k].y;
            p.x = nx; p.y = ny;
        }
        #pragma unroll
        for (int k = 0; k < 8; ++k) { A0[k] = A1[k]; C0[k] = C1[k]; }
    }
}

// ---------------- Phase 3: replay, WAVE-LOCAL transpose, zero group barriers ----------------
__global__ __launch_bounds__(256, 2) void ifs_phase3(
    const int* __restrict__ idxg, const float* __restrict__ W,
    const float* __restrict__ B, const float* __restrict__ OPS,
    const float2* __restrict__ pe, float* __restrict__ out)
{
    __shared__ u16 tile[256][COLS];                        // 16.9 KB
    __shared__ __align__(16) float sbuf[4][2][4][64][3];   // per-wave ping-pong, 12 KB
    __shared__ __align__(16) float4 tA[NF], tB[NF];
    const int tid  = threadIdx.x;
    const int c    = blockIdx.x >> 3;
    const int b0   = (blockIdx.x & 7) << 8;
    const int x8   = tid & 7, yy = tid >> 3;
    const int wv   = tid >> 6, lane = tid & 63;

    build_tbl(tA, tB, W, B, OPS, tid);
    #pragma unroll
    for (int seg = 0; seg < 4; ++seg)                      // idx re-read: L3-resident
        stage_u16(idxg, tile, c, b0, x8, yy, seg);

    float2 p = pe[(size_t)c * MB + b0 + tid];

    // wave-local store decomposition: f32x4 k covers flat words w=4*(lane+64k)
    // of this wave's 4x64x3-word group tile; step s=w/192, col r=w%192
    int s_[3];
    long long off[3];
    #pragma unroll
    for (int k = 0; k < 3; ++k) {
        const int w = 4 * (lane + 64 * k);
        s_[k] = w / 192;
        const int r = w - s_[k] * 192;
        off[k] = (long long)(c * CH + s_[k] - RM) * (MB * 3) + (b0 + wv * 64) * 3 + r;
    }
    const bool chk = (c == 0);
    __syncthreads();                                       // tile + tables visible

    for (int g = 0; g < 32; ++g) {                         // 32 groups x 4 steps
        const int buf = g & 1;
        const u32 pc = tile[tid][CMAP(g)];
        #pragma unroll
        for (int s = 0; s < 4; ++s) {
            const int f = (pc >> (4 * s)) & 7;
            const float4 w  = tA[f];
            const float4 bb = tB[f];
            const float nx = w.x * p.x + w.y * p.y + bb.x;
            const float ny = w.z * p.x + w.w * p.y + bb.y;
            p.x = nx; p.y = ny;
            sbuf[wv][buf][s][lane][0] = nx;                // stride-3 b32: 2-way free
            sbuf[wv][buf][s][lane][1] = ny;
            sbuf[wv][buf][s][lane][2] = bb.z;
        }
        __builtin_amdgcn_wave_barrier();                   // pin order: writes < reads
        // same-wave DS ops are pipe-ordered; cross-lane RAW needs no s_barrier
        const float* flat = &sbuf[wv][buf][0][0][0];
        #pragma unroll
        for (int k = 0; k < 3; ++k) {
            if (!chk || (g * 4 + s_[k]) >= RM) {
                const f32x4 v = *(const f32x4*)(flat + 4 * (lane + 64 * k));
                __builtin_nontemporal_store(v, (f32x4*)(out + off[k]));
            }
            off[k] += 4LL * (MB * 3);
        }
        __builtin_amdgcn_wave_barrier();                   // reads < next ping-pong writes
    }
}

extern "C" void kernel_launch(void* const* d_in, const int* in_sizes, int n_in,
                              void* d_out, int out_size, void* d_ws, size_t ws_size,
                              hipStream_t stream) {
    const float2* point = (const float2*)d_in[0];  // [2048,2,1]
    const float*  W     = (const float*)d_in[1];   // [8,2,2]
    const float*  B     = (const float*)d_in[2];   // [8,2,1]
    const float*  OPS   = (const float*)d_in[3];   // [8]
    const int*    idx   = (const int*)  d_in[4];   // [2048,8192]
    float*        out   = (float*)d_out;           // [(8192-51)*2048, 3]

    char* ws = (char*)d_ws;
    float4* mapsA = (float4*)(ws);                                 // 2 MB
    float2* mapsC = (float2*)(ws + (size_t)NCH * MB * 16);         // 1 MB
    float2* pe    = (float2*)(ws + (size_t)NCH * MB * 24);         // 1 MB

    ifs_phase1<<<NCH * (MB / 256), 256, 0, stream>>>(idx, W, B, mapsA, mapsC);
    ifs_phase2<<<MB / 64, 64, 0, stream>>>(point, mapsA, mapsC, pe);
    ifs_phase3<<<NCH * (MB / 256), 256, 0, stream>>>(idx, W, B, OPS, pe, out);
}

// Round 13
// 71.493 us; speedup vs baseline: 2.5775x; 1.0564x over previous
//
#include <hip/hip_runtime.h>

#define MB   2048   // model batches
#define NP   8192   // num points (scan length)
#define NF   8      // number of functions
#define RM   51     // removed leading iterations
#define NCH  64     // chunks per batch
#define CH   128    // NP / NCH, steps per chunk
#define COLS 33     // u16 words per tile row (32 used + pad)

typedef float          f32x4 __attribute__((ext_vector_type(4)));
typedef unsigned int   u32;
typedef unsigned short u16;

// word w = seg*8 + x8 (seg 0..3) holds steps 4w..4w+3, stored at col 4*x8+seg.
#define CMAP(g) ((((g) & 7) << 2) | ((g) >> 3))

// ws: mapsA float4[NCH*MB] @0 (2MB) | mapsC float2[NCH*MB] @2MB (1MB)
//     codes u32[NCH*16*MB] @3MB (8MB)

__device__ __forceinline__ void build_tbl(float4* tA, float4* tB, const float* W,
                                          const float* B, const float* OPS, int tid)
{
    if (tid < NF) {
        tA[tid] = make_float4(W[tid*4+0], W[tid*4+1], W[tid*4+2], W[tid*4+3]);
        tB[tid] = make_float4(B[tid*2+0], B[tid*2+1], OPS ? OPS[tid] : 0.f, 0.f);
    }
}

// stage one 32-step segment as nibble codes (4-bit f x4 per u16), coalesced int4
__device__ __forceinline__ void stage_u16(
    const int* __restrict__ idxg, u16 (*tile)[COLS],
    int c, int b0, int x8, int yy, int seg)
{
    #pragma unroll
    for (int p = 0; p < 8; ++p) {
        const int row = yy + p * 32;       // 8 lanes x int4 = 128B/row: coalesced
        const int4 v = *(const int4*)(idxg + (size_t)(b0 + row) * NP
                                      + c * CH + seg * 32 + x8 * 4);
        tile[row][4 * x8 + seg] = (u16)(v.x | (v.y << 4) | (v.z << 8) | (v.w << 12));
    }
}

// ---------------- K1: compose 128-step chunk maps + emit packed codes ----------------
__global__ __launch_bounds__(256, 2) void ifs_compose(
    const int* __restrict__ idxg, const float* __restrict__ W,
    const float* __restrict__ B,
    float4* __restrict__ mapsA, float2* __restrict__ mapsC, u32* __restrict__ codes)
{
    __shared__ u16 tile[256][COLS];                 // 16.9 KB
    __shared__ __align__(16) float4 tA[NF], tB[NF]; // conflict-free b128 broadcast
    const int tid = threadIdx.x;
    const int c   = blockIdx.x >> 3;
    const int b0  = (blockIdx.x & 7) << 8;
    const int b   = b0 + tid;
    const int x8  = tid & 7, yy = tid >> 3;

    build_tbl(tA, tB, W, B, nullptr, tid);
    stage_u16(idxg, tile, c, b0, x8, yy, 0);
    __syncthreads();                                // stage(0) + tables visible

    float a00 = 1.f, a01 = 0.f, a10 = 0.f, a11 = 1.f, c0 = 0.f, c1 = 0.f;
    for (int seg = 0; seg < 4; ++seg) {
        if (seg < 3) stage_u16(idxg, tile, c, b0, x8, yy, seg + 1);  // overlap
        #pragma unroll
        for (int j = 0; j < 8; ++j) {
            const u32 pc = tile[tid][CMAP(seg * 8 + j)];
            #pragma unroll
            for (int e = 0; e < 4; ++e) {
                const int f = (pc >> (4 * e)) & 7;
                const float4 w  = tA[f];
                const float4 bb = tB[f];
                const float na00 = w.x*a00 + w.y*a10;
                const float na01 = w.x*a01 + w.y*a11;
                const float na10 = w.z*a00 + w.w*a10;
                const float na11 = w.z*a01 + w.w*a11;
                const float nc0  = w.x*c0  + w.y*c1 + bb.x;
                const float nc1  = w.z*c0  + w.w*c1 + bb.y;
                a00 = na00; a01 = na01; a10 = na10; a11 = na11; c0 = nc0; c1 = nc1;
            }
        }
        __syncthreads();                            // publish staged seg
    }
    // emit packed codes: word j = steps 8j..8j+7 (low u16 = group 2j, high = 2j+1)
    #pragma unroll
    for (int j = 0; j < 16; ++j) {
        const u32 w = (u32)tile[tid][CMAP(2 * j)]
                    | ((u32)tile[tid][CMAP(2 * j + 1)] << 16);
        codes[((size_t)c * 16 + j) * MB + b] = w;   // coalesced u32 stores
    }
    mapsA[(size_t)c * MB + b] = make_float4(a00, a01, a10, a11);
    mapsC[(size_t)c * MB + b] = make_float2(c0, c1);
}

// ---------------- K2: per-thread prefix scan + replay, transpose-coalesced out ----------------
__global__ __launch_bounds__(256, 2) void ifs_replay(
    const float2* __restrict__ point, const float4* __restrict__ mapsA,
    const float2* __restrict__ mapsC, const u32* __restrict__ codes,
    const float* __restrict__ W, const float* __restrict__ B,
    const float* __restrict__ OPS, float* __restrict__ out)
{
    __shared__ __align__(16) float sbuf[2][4][256][3];   // ping-pong transpose 24 KB
    __shared__ __align__(16) float4 tA[NF], tB[NF];
    const int tid = threadIdx.x;
    const int c   = blockIdx.x >> 3;
    const int b0  = (blockIdx.x & 7) << 8;
    const int b   = b0 + tid;

    build_tbl(tA, tB, W, B, OPS, tid);

    // codes straight to registers: 16 coalesced u32 loads (L2/L3-resident)
    u32 cw[16];
    #pragma unroll
    for (int j = 0; j < 16; ++j)
        cw[j] = codes[((size_t)c * 16 + j) * MB + b];

    // per-thread prefix scan over chunks 0..c-1 (block-uniform trip count)
    float2 p = point[b];
    {
        int k = 0;
        float4 Ab[8]; float2 Cb[8];
        while (k + 8 <= c) {
            #pragma unroll
            for (int j = 0; j < 8; ++j) {
                Ab[j] = mapsA[(size_t)(k + j) * MB + b];
                Cb[j] = mapsC[(size_t)(k + j) * MB + b];
            }
            #pragma unroll
            for (int j = 0; j < 8; ++j) {
                const float nx = Ab[j].x * p.x + Ab[j].y * p.y + Cb[j].x;
                const float ny = Ab[j].z * p.x + Ab[j].w * p.y + Cb[j].y;
                p.x = nx; p.y = ny;
            }
            k += 8;
        }
        for (; k < c; ++k) {
            const float4 A = mapsA[(size_t)k * MB + b];
            const float2 C = mapsC[(size_t)k * MB + b];
            const float nx = A.x * p.x + A.y * p.y + C.x;
            const float ny = A.z * p.x + A.w * p.y + C.y;
            p.x = nx; p.y = ny;
        }
    }

    // store-side decomposition: f32x4 k covers flat words w=4*(tid+256k) of the
    // 4x256x3-word group tile; step s=w/768, col r=w%768
    int s_[3];
    long long off[3];
    #pragma unroll
    for (int k = 0; k < 3; ++k) {
        const int w = 4 * (tid + 256 * k);
        s_[k] = w / 768;
        const int r = w - s_[k] * 768;
        off[k] = (long long)(c * CH + s_[k] - RM) * (MB * 3) + b0 * 3 + r;
    }
    const bool chk = (c == 0);
    __syncthreads();                                     // tables visible

    for (int g = 0; g < 32; ++g) {                       // 32 groups x 4 steps
        const int buf = g & 1;
        const u32 pc = cw[g >> 1] >> ((g & 1) * 16);     // 4 nibbles for this group
        #pragma unroll
        for (int s = 0; s < 4; ++s) {
            const int f = (pc >> (4 * s)) & 7;
            const float4 w  = tA[f];
            const float4 bb = tB[f];
            const float nx = w.x * p.x + w.y * p.y + bb.x;
            const float ny = w.z * p.x + w.w * p.y + bb.y;
            p.x = nx; p.y = ny;
            sbuf[buf][s][tid][0] = nx;                   // stride-3 b32: 2-way = free
            sbuf[buf][s][tid][1] = ny;
            sbuf[buf][s][tid][2] = bb.z;
        }
        __syncthreads();                                 // one barrier per group
        const float* flat = &sbuf[buf][0][0][0];
        #pragma unroll
        for (int k = 0; k < 3; ++k) {
            if (!chk || (g * 4 + s_[k]) >= RM) {
                const f32x4 v = *(const f32x4*)(flat + 4 * (tid + 256 * k));
                __builtin_nontemporal_store(v, (f32x4*)(out + off[k]));
            }
            off[k] += 4LL * (MB * 3);
        }
    }
}

extern "C" void kernel_launch(void* const* d_in, const int* in_sizes, int n_in,
                              void* d_out, int out_size, void* d_ws, size_t ws_size,
                              hipStream_t stream) {
    const float2* point = (const float2*)d_in[0];  // [2048,2,1]
    const float*  W     = (const float*)d_in[1];   // [8,2,2]
    const float*  B     = (const float*)d_in[2];   // [8,2,1]
    const float*  OPS   = (const float*)d_in[3];   // [8]
    const int*    idx   = (const int*)  d_in[4];   // [2048,8192]
    float*        out   = (float*)d_out;           // [(8192-51)*2048, 3]

    char* ws = (char*)d_ws;
    float4* mapsA = (float4*)(ws);                                 // 2 MB
    float2* mapsC = (float2*)(ws + (size_t)NCH * MB * 16);         // 1 MB
    u32*    codes = (u32*)   (ws + (size_t)NCH * MB * 24);         // 8 MB

    ifs_compose<<<NCH * (MB / 256), 256, 0, stream>>>(idx, W, B, mapsA, mapsC, codes);
    ifs_replay <<<NCH * (MB / 256), 256, 0, stream>>>(point, mapsA, mapsC, codes,
                                                      W, B, OPS, out);
}